// Round 2
// baseline (278.343 us; speedup 1.0000x reference)
//
#include <hip/hip_runtime.h>
#include <hip/hip_bf16.h>
#include <math.h>

// PaGCN forward, restructured:
//   h0 = relu(AM ⊙ spmm(adjZ, (M⊙x)@W0) + b0)      (spmm gathers 128 bf16 feats)
//   h1 = relu(AM ⊙ spmm(adjZ, (M⊙h0)@W1) + b1)     (spmm gathers 64 bf16 feats)
//   out = log_softmax(spmm(adj, h1@W2) + b2)        (spmm gathers 40 bf16 feats)
//
// R10: latency-surface pass. Everything is L3-resident (R0 FETCH 14MB < x's
// 25.6MB) so the pipeline is latency/serialization bound, not BW bound.
//  - Absolute-offset CSR: scan emits cmabs[chunk][bin] = rp[bin]+prefix (u32),
//    so scatter does ONE random per-edge gather (R9 did two: rp[r] and
//    cm[chunk][r], each a 64B line per lane).
//  - scan split into scan_sum (read-only over cntmat -> loads pipeline; R9's
//    scan_part2 read+wrote the same array -> alias-serialized 49 iters) and
//    scan_fin (writes cmabs, different array). scan_top folded into scan_fin
//    (block's 1024-bin group is uniform -> wave-redundant bsums prefix).
//    11 launches -> 10.
//  - spmm MLP: spmm128 burst 8->16 (avg deg = 16 -> one latency round/row);
//    spmm64 4 edges/wave via uint2 (16 lanes x 8B per row, 2x in-flight);
//    spmm40 8 q-steps (24 edges in flight).
// Carried from R9: LDS counting-sort histogram (no global atomics; 98KB u16
// pair bins, chunk 16384 < 2^16), hist+gemm0 fusion, no-LDS MFMA GEMMs,
// bf16 gather targets, M folded into spmm128 epilogue, clamped epilogues.

typedef __attribute__((ext_vector_type(8))) short bf16x8;
typedef __attribute__((ext_vector_type(4))) float f32x4;

#define HIST_EPB_LOG 14
#define HIST_EPB 16384          // edges per hist block (fits u16 counters)
#define NBINS 50176             // >= N, = 49*1024, even (u16-pair packing)

__device__ __forceinline__ float rl_f(float v, int j) {
    return __builtin_bit_cast(float,
        __builtin_amdgcn_readlane(__builtin_bit_cast(int, v), j));
}
__device__ __forceinline__ int rl_i(int v, int j) {
    return __builtin_amdgcn_readlane(v, j);
}
__device__ __forceinline__ unsigned short f2bf(float f) {
    unsigned u = __builtin_bit_cast(unsigned, f);
    u += 0x7fffu + ((u >> 16) & 1u);   // round-to-nearest-even
    return (unsigned short)(u >> 16);
}
__device__ __forceinline__ unsigned pack2bf(float lo, float hi) {
    return (unsigned)f2bf(lo) | ((unsigned)f2bf(hi) << 16);
}
__device__ __forceinline__ float bf_lo(unsigned u) {
    return __builtin_bit_cast(float, u << 16);
}
__device__ __forceinline__ float bf_hi(unsigned u) {
    return __builtin_bit_cast(float, u & 0xffff0000u);
}
__device__ __forceinline__ float clampf(float v) {   // NaN -> -1e30 (finite)
    return fminf(fmaxf(v, -1e30f), 1e30f);
}

// ---------------- W prep: Wt[n][k] = bf16(W[k][n]), n zero-padded ----------------

__global__ void prep_wt(const float* __restrict__ W0, const float* __restrict__ W1,
                        const float* __restrict__ W2,
                        unsigned short* __restrict__ wt0, unsigned short* __restrict__ wt1,
                        unsigned short* __restrict__ wt2) {
    int idx = blockIdx.x * 256 + threadIdx.x;
    if (idx < 128 * 128) {                       // wt0: [128][128]
        int nn = idx >> 7, k = idx & 127;
        wt0[idx] = f2bf(W0[k * 128 + nn]);
    }
    idx -= 128 * 128;
    if (idx >= 0 && idx < 64 * 128) {            // wt1: [64][128]
        int nn = idx >> 7, k = idx & 127;
        wt1[idx] = f2bf(W1[k * 64 + nn]);
    }
    idx -= 64 * 128;
    if (idx >= 0 && idx < 48 * 64) {             // wt2: [48][64], n>=40 zero
        int nn = idx >> 6, k = idx & 63;
        wt2[idx] = (nn < 40) ? f2bf(W2[k * 40 + nn]) : (unsigned short)0;
    }
}

// ---------------- MFMA GEMM body (no LDS, no barriers) ----------------
// 4 waves per 256-thread group, each wave computes 16 rows x COLS via
// 16x16x32 bf16 MFMA. tid is the position within the 256-thread group so
// the body can be embedded in larger blocks (hist_gemm0 runs 4 groups).
// Fragment maps (HW-verified per guide): A[m=lane&15][k=(lane>>4)*8+j],
// B[k=(lane>>4)*8+j][n=lane&15], D[row=(lane>>4)*4+reg][col=lane&15].

template <int K, int COLS, int NTPAD, bool ABF16, bool MSCALE>
__device__ __forceinline__ void gemm_mfma_body(const void* __restrict__ Asrc,
                                               const float* __restrict__ Mv,
                                               const unsigned short* __restrict__ Wt,
                                               unsigned short* __restrict__ outp,
                                               int n, int bid, int tid) {
    constexpr int KS = K / 32;
    const int lane = tid & 63;
    const int wid = tid >> 6;
    const int m15 = lane & 15;
    const int q = lane >> 4;
    const int rA = bid * 64 + wid * 16 + m15;   // row this lane supplies to A

    bf16x8 a[KS];
    if constexpr (ABF16) {
        const unsigned short* A = (const unsigned short*)Asrc;
#pragma unroll
        for (int ks = 0; ks < KS; ++ks) {
            uint4 z = make_uint4(0u, 0u, 0u, 0u);
            if (rA < n) z = *(const uint4*)(A + (size_t)rA * K + ks * 32 + q * 8);
            a[ks] = __builtin_bit_cast(bf16x8, z);
        }
    } else {
        const float* A = (const float*)Asrc;
        float m = 1.0f;
        if constexpr (MSCALE) { if (rA < n) m = Mv[rA]; }
#pragma unroll
        for (int ks = 0; ks < KS; ++ks) {
            float4 lo = make_float4(0.f, 0.f, 0.f, 0.f);
            float4 hi = make_float4(0.f, 0.f, 0.f, 0.f);
            if (rA < n) {
                lo = *(const float4*)(A + (size_t)rA * K + ks * 32 + q * 8);
                hi = *(const float4*)(A + (size_t)rA * K + ks * 32 + q * 8 + 4);
            }
            union { bf16x8 v; unsigned short u[8]; } pk;
            pk.u[0] = f2bf(lo.x * m); pk.u[1] = f2bf(lo.y * m);
            pk.u[2] = f2bf(lo.z * m); pk.u[3] = f2bf(lo.w * m);
            pk.u[4] = f2bf(hi.x * m); pk.u[5] = f2bf(hi.y * m);
            pk.u[6] = f2bf(hi.z * m); pk.u[7] = f2bf(hi.w * m);
            a[ks] = pk.v;
        }
    }

#pragma unroll
    for (int nt = 0; nt < NTPAD / 16; ++nt) {
        f32x4 acc = {0.f, 0.f, 0.f, 0.f};
        const int bn = nt * 16 + m15;           // col this lane supplies to B
#pragma unroll
        for (int ks = 0; ks < KS; ++ks) {
            const uint4 z = *(const uint4*)(Wt + (size_t)bn * K + ks * 32 + q * 8);
            const bf16x8 b = __builtin_bit_cast(bf16x8, z);
            acc = __builtin_amdgcn_mfma_f32_16x16x32_bf16(a[ks], b, acc, 0, 0, 0);
        }
        const int gc = nt * 16 + m15;
#pragma unroll
        for (int rr = 0; rr < 4; ++rr) {
            const int gr = bid * 64 + wid * 16 + q * 4 + rr;
            bool ok = gr < n;
            if constexpr (NTPAD != COLS) ok = ok && (gc < COLS);
            if (ok) outp[(size_t)gr * COLS + gc] = f2bf(clampf(acc[rr]));
        }
    }
}

template <int K, int COLS, int NTPAD, bool ABF16, bool MSCALE>
__launch_bounds__(256)
__global__ void gemm_mfma(const void* __restrict__ A, const float* __restrict__ Mv,
                          const unsigned short* __restrict__ Wt,
                          unsigned short* __restrict__ out, int n) {
    gemm_mfma_body<K, COLS, NTPAD, ABF16, MSCALE>(A, Mv, Wt, out, n, blockIdx.x,
                                                  threadIdx.x);
}

// ---------------- fused LDS histogram (counting-sort rank) + gemm0 ----------------
// Blocks [0,NB): per-chunk LDS histogram over all bins (packed u16 pairs).
// Blocks [NB, NB+ceil(gemmBlocks/4)): gemm0, 4x 256-thread groups per block.

__launch_bounds__(1024)
__global__ void hist_gemm0(const int* __restrict__ row,
                           unsigned short* __restrict__ cntmat,
                           unsigned short* __restrict__ lrank, int E, int NB,
                           const float* __restrict__ x, const float* __restrict__ Mv,
                           const unsigned short* __restrict__ Wt0,
                           unsigned short* __restrict__ t_buf, int n) {
    __shared__ unsigned hcnt[NBINS / 2];        // 98KB: u16 bin pairs
    const int blk = blockIdx.x;
    const int t = threadIdx.x;
    if (blk < NB) {
        for (int i = t; i < NBINS / 2; i += 1024) hcnt[i] = 0u;
        __syncthreads();
        const int s = blk << HIST_EPB_LOG;
        const int e = min(E, s + HIST_EPB);
        for (int i = s + t; i < e; i += 1024) {
            const int r = row[i];               // r < n <= NBINS (host guarantees)
            const unsigned sh = (unsigned)(r & 1) << 4;
            const unsigned old = atomicAdd(&hcnt[r >> 1], 1u << sh);
            lrank[i] = (unsigned short)((old >> sh) & 0xffffu);
        }
        __syncthreads();
        unsigned* dst = (unsigned*)(cntmat + (size_t)blk * NBINS);
        for (int i = t; i < NBINS / 2; i += 1024) dst[i] = hcnt[i];
    } else {
        const int sub = t >> 8;                 // 4 gemm groups per block
        gemm_mfma_body<128, 128, 128, false, true>(x, Mv, Wt0, t_buf, n,
                                                   (blk - NB) * 4 + sub, t & 255);
    }
}

// ---------------- scan phase 1: row totals (read-only over cntmat) ----------------
// Block covers 1024 bins (256 thr x 4). Loads are independent -> pipelined.

__global__ void scan_sum(const unsigned short* __restrict__ cm, int* __restrict__ rp,
                         int* __restrict__ bsums, int n, int NB) {
    __shared__ int sdata[256];
    const int t = threadIdx.x;
    const int base = blockIdx.x * 1024 + t * 4;
    unsigned s0 = 0, s1 = 0, s2 = 0, s3 = 0;
    for (int b = 0; b < NB; ++b) {
        const uint2 c = *(const uint2*)&cm[(size_t)b * NBINS + base];
        s0 += c.x & 0xffffu; s1 += c.x >> 16;
        s2 += c.y & 0xffffu; s3 += c.y >> 16;
    }
    int v[4] = {(int)s0, (int)s1, (int)s2, (int)s3};
    const int tsum = v[0] + v[1] + v[2] + v[3];
    sdata[t] = tsum;
    __syncthreads();
    for (int off = 1; off < 256; off <<= 1) {
        int xv = (t >= off) ? sdata[t - off] : 0;
        __syncthreads();
        sdata[t] += xv;
        __syncthreads();
    }
    int run = sdata[t] - tsum;
    if (t == 255) bsums[blockIdx.x] = sdata[t];
#pragma unroll
    for (int i = 0; i < 4; ++i) {
        if (base + i < n) rp[base + i] = run;
        run += v[i];
    }
}

// ---------------- scan phase 2: finalize rp + absolute chunk offsets ----------------
// cmabs[b][i] = rp_final[i] + sum_{b'<b} cm[b'][i]  (u32). The bsums prefix
// for this block's 1024-bin group is block-uniform -> computed wave-redundantly
// (folds the old scan_top kernel away). Reads cm, writes cmabs (distinct
// arrays -> loop pipelines).

__launch_bounds__(256)
__global__ void scan_fin(const unsigned short* __restrict__ cm,
                         unsigned* __restrict__ cmabs, int* __restrict__ rp,
                         const int* __restrict__ bsums, int n, int NB, int E) {
    const int lane = threadIdx.x & 63;
    const int myblk = blockIdx.x >> 2;          // 1024-bin group (scan_sum block)
    int bv = (lane < myblk) ? bsums[lane] : 0;  // myblk <= 48 < 64
#pragma unroll
    for (int off = 32; off; off >>= 1) bv += __shfl_xor(bv, off);
    const int i = blockIdx.x * 256 + threadIdx.x;
    if (i < n) {
        int run = rp[i] + bv;
        rp[i] = run;
        for (int b = 0; b < NB; ++b) {
            cmabs[(size_t)b * NBINS + i] = (unsigned)run;
            run += (int)cm[(size_t)b * NBINS + i];
        }
    }
    if (blockIdx.x == 0 && threadIdx.x == 0) rp[n] = E;
}

// ---------------- scatter (atomic-free, ONE random gather per edge) ----------------

__global__ void scatter_kernel(const int* __restrict__ row, const int* __restrict__ col,
                               const float* __restrict__ vA, const float* __restrict__ vZ,
                               const unsigned* __restrict__ cmabs,
                               const unsigned short* __restrict__ lrank,
                               float* __restrict__ packed, int E) {
    int e = blockIdx.x * blockDim.x + threadIdx.x;
    if (e >= E) return;
    const int r = row[e];
    const int pos = (int)(cmabs[(size_t)(e >> HIST_EPB_LOG) * NBINS + r]
                          + (unsigned)lrank[e]);
    float3 pk;
    pk.x = __int_as_float(col[e]);
    pk.y = vZ[e];
    pk.z = vA[e];
    *(float3*)&packed[(size_t)3 * pos] = pk;
}

// ---------------- SpMM F=128: wave/row, 16-deep bursts; out = M⊙relu(...) bf16 ----------------

__launch_bounds__(256)
__global__ void spmm128_kernel(const float* __restrict__ packed,
                               const int* __restrict__ rp, const unsigned short* __restrict__ X,
                               const float* __restrict__ AM, const float* __restrict__ Mv,
                               const float* __restrict__ bias,
                               unsigned short* __restrict__ out, int n) {
    const int lane = threadIdx.x & 63;
    const int r = (int)((blockIdx.x * (unsigned)blockDim.x + threadIdx.x) >> 6);
    if (r >= n) return;
    const int s = __builtin_amdgcn_readfirstlane(rp[r]);
    const int e = __builtin_amdgcn_readfirstlane(rp[r + 1]);

    float acc0 = 0.0f, acc1 = 0.0f;
    for (int base = s; base < e; base += 64) {
        const int nn = min(64, e - base);
        int ci = 0; float vf = 0.0f;
        if (lane < nn) {
            const float3 pk = *(const float3*)&packed[(size_t)3 * (base + lane)];
            ci = __builtin_bit_cast(int, pk.x);
            vf = pk.y;
        }
        int j = 0;
        for (; j + 16 <= nn; j += 16) {         // avg deg = 16: one latency round
            unsigned u[16];
#pragma unroll
            for (int q = 0; q < 16; ++q) {
                const int cq = rl_i(ci, j + q);
                u[q] = *(const unsigned*)(X + (size_t)cq * 128 + lane * 2);
            }
#pragma unroll
            for (int q = 0; q < 16; ++q) {
                const float vq = rl_f(vf, j + q);
                acc0 += vq * bf_lo(u[q]);
                acc1 += vq * bf_hi(u[q]);
            }
        }
        for (; j + 8 <= nn; j += 8) {
            unsigned u[8];
#pragma unroll
            for (int q = 0; q < 8; ++q) {
                const int cq = rl_i(ci, j + q);
                u[q] = *(const unsigned*)(X + (size_t)cq * 128 + lane * 2);
            }
#pragma unroll
            for (int q = 0; q < 8; ++q) {
                const float vq = rl_f(vf, j + q);
                acc0 += vq * bf_lo(u[q]);
                acc1 += vq * bf_hi(u[q]);
            }
        }
        for (; j < nn; ++j) {
            const int cq = rl_i(ci, j);
            const float vq = rl_f(vf, j);
            const unsigned u = *(const unsigned*)(X + (size_t)cq * 128 + lane * 2);
            acc0 += vq * bf_lo(u);
            acc1 += vq * bf_hi(u);
        }
    }

    const float am = AM[r];
    const float mr = Mv[r];   // fold M (>=0): M⊙relu(y) = relu(M⊙y)
    const float o0 = fminf(fmaxf((acc0 * am + bias[2 * lane]) * mr, 0.0f), 1e30f);
    const float o1 = fminf(fmaxf((acc1 * am + bias[2 * lane + 1]) * mr, 0.0f), 1e30f);
    ((unsigned*)out)[(size_t)r * 64 + lane] = pack2bf(o0, o1);
}

// ---------------- SpMM F=64: 4 edges/wave (uint2/lane); out = relu(...) bf16 ----------------

__launch_bounds__(256)
__global__ void spmm64_kernel(const float* __restrict__ packed,
                              const int* __restrict__ rp, const unsigned short* __restrict__ X,
                              const float* __restrict__ AM, const float* __restrict__ bias,
                              unsigned short* __restrict__ out, int n) {
    const int lane = threadIdx.x & 63;
    const int g = lane >> 4;        // edge slot 0..3
    const int ls = lane & 15;       // feat quad: feats 4*ls..4*ls+3
    const int r = (int)((blockIdx.x * (unsigned)blockDim.x + threadIdx.x) >> 6);
    if (r >= n) return;
    const int s = __builtin_amdgcn_readfirstlane(rp[r]);
    const int e = __builtin_amdgcn_readfirstlane(rp[r + 1]);

    float a0 = 0.0f, a1 = 0.0f, a2 = 0.0f, a3 = 0.0f;
    for (int base = s; base < e; base += 64) {
        const int nn = min(64, e - base);
        int ci = 0; float vf = 0.0f;
        if (lane < nn) {
            const float3 pk = *(const float3*)&packed[(size_t)3 * (base + lane)];
            ci = __builtin_bit_cast(int, pk.x);
            vf = pk.y;
        }
        for (int j = 0; j < nn; j += 16) {
#pragma unroll
            for (int q = 0; q < 4; ++q) {
                const int jj = j + 4 * q + g;
                const bool ok = jj < nn;
                const int idx = jj & 63;
                const int c = __shfl(ci, idx);
                const float v = __shfl(vf, idx);
                if (ok) {
                    const uint2 u = *(const uint2*)(X + (size_t)c * 64 + ls * 4);
                    a0 += v * bf_lo(u.x);
                    a1 += v * bf_hi(u.x);
                    a2 += v * bf_lo(u.y);
                    a3 += v * bf_hi(u.y);
                }
            }
        }
    }
    a0 += __shfl_xor(a0, 16); a0 += __shfl_xor(a0, 32);
    a1 += __shfl_xor(a1, 16); a1 += __shfl_xor(a1, 32);
    a2 += __shfl_xor(a2, 16); a2 += __shfl_xor(a2, 32);
    a3 += __shfl_xor(a3, 16); a3 += __shfl_xor(a3, 32);

    if (lane < 16) {
        const float am = AM[r];
        const float o0 = fminf(fmaxf(a0 * am + bias[4 * ls + 0], 0.0f), 1e30f);
        const float o1 = fminf(fmaxf(a1 * am + bias[4 * ls + 1], 0.0f), 1e30f);
        const float o2 = fminf(fmaxf(a2 * am + bias[4 * ls + 2], 0.0f), 1e30f);
        const float o3 = fminf(fmaxf(a3 * am + bias[4 * ls + 3], 0.0f), 1e30f);
        uint2 w;
        w.x = pack2bf(o0, o1);
        w.y = pack2bf(o2, o3);
        *(uint2*)((unsigned*)out + (size_t)r * 32 + ls * 2) = w;
    }
}

// ---------------- SpMM F=40 + log_softmax: 3 edges/wave, 24 in flight ----------------

__launch_bounds__(256)
__global__ void spmm40_kernel(const float* __restrict__ packed,
                              const int* __restrict__ rp, const unsigned short* __restrict__ X,
                              const float* __restrict__ bias,
                              float* __restrict__ out, int n) {
    const int lane = threadIdx.x & 63;
    const int g = lane / 20;
    const int ls = lane - 20 * g;
    const bool active = g < 3;
    const int r = (int)((blockIdx.x * (unsigned)blockDim.x + threadIdx.x) >> 6);
    if (r >= n) return;
    const int s = __builtin_amdgcn_readfirstlane(rp[r]);
    const int e = __builtin_amdgcn_readfirstlane(rp[r + 1]);

    float acc0 = 0.0f, acc1 = 0.0f;
    for (int base = s; base < e; base += 64) {
        const int nn = min(64, e - base);
        int ci = 0; float vf = 0.0f;
        if (lane < nn) {
            const float3 pk = *(const float3*)&packed[(size_t)3 * (base + lane)];
            ci = __builtin_bit_cast(int, pk.x);
            vf = pk.z;                   // adj (not adjZ) values
        }
        for (int j = 0; j < nn; j += 24) {
#pragma unroll
            for (int q = 0; q < 8; ++q) {
                const int jj = j + 3 * q + g;
                const bool ok = active && jj < nn;
                const int idx = jj & 63;
                const int c = __shfl(ci, idx);
                const float v = __shfl(vf, idx);
                if (ok) {
                    const unsigned u = *(const unsigned*)(X + (size_t)c * 40 + ls * 2);
                    acc0 += v * bf_lo(u);
                    acc1 += v * bf_hi(u);
                }
            }
        }
    }
    {
        const float a1 = __shfl(acc0, (lane + 20) & 63);
        const float a2 = __shfl(acc0, (lane + 40) & 63);
        const float b1 = __shfl(acc1, (lane + 20) & 63);
        const float b2 = __shfl(acc1, (lane + 40) & 63);
        acc0 += a1 + a2;
        acc1 += b1 + b2;
    }

    const bool own = lane < 20;
    const float vv0 = own ? fminf(fmaxf(acc0 + bias[2 * ls], -1e30f), 1e30f) : -INFINITY;
    const float vv1 = own ? fminf(fmaxf(acc1 + bias[2 * ls + 1], -1e30f), 1e30f) : -INFINITY;
    float mx = fmaxf(vv0, vv1);
#pragma unroll
    for (int off = 32; off > 0; off >>= 1) mx = fmaxf(mx, __shfl_xor(mx, off));
    float sum = own ? (expf(vv0 - mx) + expf(vv1 - mx)) : 0.0f;
#pragma unroll
    for (int off = 32; off > 0; off >>= 1) sum += __shfl_xor(sum, off);
    if (own) {
        const float lse = mx + logf(sum);
        *(float2*)(out + (size_t)r * 40 + ls * 2) = make_float2(vv0 - lse, vv1 - lse);
    }
}

// ---------------- launch ----------------

extern "C" void kernel_launch(void* const* d_in, const int* in_sizes, int n_in,
                              void* d_out, int out_size, void* d_ws, size_t ws_size,
                              hipStream_t stream) {
    const float* x    = (const float*)d_in[0];
    const float* M    = (const float*)d_in[1];
    const float* AM   = (const float*)d_in[2];
    const float* adjv = (const float*)d_in[3];
    const float* adjZ = (const float*)d_in[4];
    const float* W0   = (const float*)d_in[5];
    const float* b0   = (const float*)d_in[6];
    const float* W1   = (const float*)d_in[7];
    const float* b1   = (const float*)d_in[8];
    const float* W2   = (const float*)d_in[9];
    const float* b2   = (const float*)d_in[10];
    const int* row    = (const int*)d_in[11];
    const int* col    = (const int*)d_in[12];
    float* out = (float*)d_out;

    const int n = in_sizes[1];   // N  (must be <= NBINS = 50176)
    const int E = in_sizes[3];   // edges

    // workspace layout (~61 MB):
    // t region (N*128 floats): t_buf bf16 (first half) + Wt arrays (tail)
    float* t_f   = (float*)d_ws;
    unsigned short* t_buf = (unsigned short*)t_f;           // N*128 bf16 gather target
    unsigned short* wt0 = t_buf + (size_t)n * 128;          // 128*128 (16B-aligned)
    unsigned short* wt1 = wt0 + 128 * 128;                  // 64*128
    unsigned short* wt2 = wt1 + 64 * 128;                   // 48*64
    float* h_f   = t_f + (size_t)n * 128;                   // N*128 floats reserved
    unsigned short* h_buf = (unsigned short*)h_f;           // bf16 h0 / h1
    // lrank + cntmat + cmabs alias the h region (dead before spmm128 writes h_buf)
    unsigned short* lrank  = (unsigned short*)h_f;          // E u16 local ranks
    unsigned short* cntmat = lrank + (size_t)E;             // [NB][NBINS] u16
    unsigned* cmabs = (unsigned*)(cntmat + (size_t)64 * NBINS);  // [NB][NBINS] u32
    int* rp      = (int*)(h_f + (size_t)n * 128);           // N+1
    int* bsums   = rp + (n + 1);                            // 64
    float* packed = (float*)(bsums + 64);                   // E*3 floats

    const int NB = (E + HIST_EPB - 1) >> HIST_EPB_LOG;      // hist chunks (<=49)
    const int gemmBlocks = (n + 63) / 64;                   // 4-wave gemm groups
    const int gemmB4 = (gemmBlocks + 3) / 4;                // 1024-thr gemm blocks

    prep_wt<<<(128 * 128 + 64 * 128 + 48 * 64 + 255) / 256, 256, 0, stream>>>(
        W0, W1, W2, wt0, wt1, wt2);

    // fused LDS histogram (rank+count, no global atomics) + gemm0 MFMA
    hist_gemm0<<<NB + gemmB4, 1024, 0, stream>>>(row, cntmat, lrank, E, NB,
                                                 x, M, wt0, t_buf, n);

    const int nblk = (n + 1023) >> 10;  // <=64; nblk*1024 <= NBINS
    scan_sum<<<nblk, 256, 0, stream>>>(cntmat, rp, bsums, n, NB);
    scan_fin<<<(n + 255) / 256, 256, 0, stream>>>(cntmat, cmabs, rp, bsums, n, NB, E);
    scatter_kernel<<<(E + 255) / 256, 256, 0, stream>>>(row, col, adjv, adjZ,
                                                        cmabs, lrank, packed, E);

    const int spmmBlocks = (n + 3) / 4;   // 4 rows (waves) per block

    // layer 0 aggregate: h_buf = M⊙relu(AM⊙agg+b0) bf16 (overwrites lrank/cmabs alias)
    spmm128_kernel<<<spmmBlocks, 256, 0, stream>>>(packed, rp, t_buf, AM, M, b0, h_buf, n);
    // layer 1: t_buf = h_buf@W1 bf16 (M already folded)
    gemm_mfma<128, 64, 64, true, false><<<gemmBlocks, 256, 0, stream>>>(h_buf, nullptr, wt1,
                                                                        t_buf, n);
    spmm64_kernel<<<spmmBlocks, 256, 0, stream>>>(packed, rp, t_buf, AM, b1, h_buf, n);
    // layer 2: t_buf = h1@W2 bf16 (stride 40)
    gemm_mfma<64, 40, 48, true, false><<<gemmBlocks, 256, 0, stream>>>(h_buf, nullptr, wt2,
                                                                       t_buf, n);
    spmm40_kernel<<<spmmBlocks, 256, 0, stream>>>(packed, rp, t_buf, b2, out, n);
}

// Round 3
// 269.917 us; speedup vs baseline: 1.0312x; 1.0312x over previous
//
#include <hip/hip_runtime.h>
#include <hip/hip_bf16.h>
#include <math.h>

// PaGCN forward, restructured:
//   h0 = relu(AM ⊙ spmm(adjZ, (M⊙x)@W0) + b0)      (spmm gathers 128 bf16 feats)
//   h1 = relu(AM ⊙ spmm(adjZ, (M⊙h0)@W1) + b1)     (spmm gathers 64 bf16 feats)
//   out = log_softmax(spmm(adj, h1@W2) + b2)        (spmm gathers 40 bf16 feats)
//
// R11: phase-structure pass (R10's inner-loop tuning was flat -> the fat is
// serialization + intermediate traffic, not spmm inner loops).
//  - scan_sum+scan_fin fused into ONE scan_one kernel: 196 blocks (all
//    co-resident on 256 CUs -> publish/poll via device-scope u64 atomics is
//    deadlock-free and XCD-coherent; no dispatch-order assumption: only
//    residency, which grid<=capacity guarantees). Each block owns 256 bins:
//    totals -> block scan -> publish group total -> poll earlier groups ->
//    final rp + absolute cmabs. -1 launch, -1 drain bubble, no rp round-trip.
//  - HIST_EPB 16384->32768 (rank<2^16 ok, u16 pair counters can't carry:
//    32768<65536): NB 49->25, cntmat 4.9->2.45MB, cmabs 9.8->5MB.
//  - packed float3 -> cz uint2{col,vZ} + va float: spmm128/64 do one aligned
//    8B load/lane (was 12B float3 straddling lines); spmm read traffic
//    28.8->22.4MB.
//  - hist LDS zero/flush vectorized uint4.
// Carried: LDS counting-sort hist (no global atomics), hist+gemm0 fusion,
// no-LDS MFMA GEMMs (W L1-resident), bf16 gather targets, M folded into
// spmm128 epilogue, clamped epilogues, 16-deep spmm128 bursts.

typedef __attribute__((ext_vector_type(8))) short bf16x8;
typedef __attribute__((ext_vector_type(4))) float f32x4;

#define HIST_EPB_LOG 15
#define HIST_EPB 32768          // edges per hist block (< 2^16: u16-safe)
#define NBINS 50176             // >= N, = 196*256, even (u16-pair packing)
#define NBMAX 32                // reserved chunk capacity in workspace
#define SCAN_BLOCKS 196         // 256 bins per block = 50176

__device__ __forceinline__ float rl_f(float v, int j) {
    return __builtin_bit_cast(float,
        __builtin_amdgcn_readlane(__builtin_bit_cast(int, v), j));
}
__device__ __forceinline__ int rl_i(int v, int j) {
    return __builtin_amdgcn_readlane(v, j);
}
__device__ __forceinline__ unsigned short f2bf(float f) {
    unsigned u = __builtin_bit_cast(unsigned, f);
    u += 0x7fffu + ((u >> 16) & 1u);   // round-to-nearest-even
    return (unsigned short)(u >> 16);
}
__device__ __forceinline__ unsigned pack2bf(float lo, float hi) {
    return (unsigned)f2bf(lo) | ((unsigned)f2bf(hi) << 16);
}
__device__ __forceinline__ float bf_lo(unsigned u) {
    return __builtin_bit_cast(float, u << 16);
}
__device__ __forceinline__ float bf_hi(unsigned u) {
    return __builtin_bit_cast(float, u & 0xffff0000u);
}
__device__ __forceinline__ float clampf(float v) {   // NaN -> -1e30 (finite)
    return fminf(fmaxf(v, -1e30f), 1e30f);
}

// ---------------- W prep: Wt[n][k] = bf16(W[k][n]), n zero-padded ----------------

__global__ void prep_wt(const float* __restrict__ W0, const float* __restrict__ W1,
                        const float* __restrict__ W2,
                        unsigned short* __restrict__ wt0, unsigned short* __restrict__ wt1,
                        unsigned short* __restrict__ wt2) {
    int idx = blockIdx.x * 256 + threadIdx.x;
    if (idx < 128 * 128) {                       // wt0: [128][128]
        int nn = idx >> 7, k = idx & 127;
        wt0[idx] = f2bf(W0[k * 128 + nn]);
    }
    idx -= 128 * 128;
    if (idx >= 0 && idx < 64 * 128) {            // wt1: [64][128]
        int nn = idx >> 7, k = idx & 127;
        wt1[idx] = f2bf(W1[k * 64 + nn]);
    }
    idx -= 64 * 128;
    if (idx >= 0 && idx < 48 * 64) {             // wt2: [48][64], n>=40 zero
        int nn = idx >> 6, k = idx & 63;
        wt2[idx] = (nn < 40) ? f2bf(W2[k * 40 + nn]) : (unsigned short)0;
    }
}

// ---------------- MFMA GEMM body (no LDS, no barriers) ----------------
// 4 waves per 256-thread group, each wave computes 16 rows x COLS via
// 16x16x32 bf16 MFMA. tid is the position within the 256-thread group so
// the body can be embedded in larger blocks (hist_gemm0 runs 4 groups).
// Fragment maps (HW-verified per guide): A[m=lane&15][k=(lane>>4)*8+j],
// B[k=(lane>>4)*8+j][n=lane&15], D[row=(lane>>4)*4+reg][col=lane&15].

template <int K, int COLS, int NTPAD, bool ABF16, bool MSCALE>
__device__ __forceinline__ void gemm_mfma_body(const void* __restrict__ Asrc,
                                               const float* __restrict__ Mv,
                                               const unsigned short* __restrict__ Wt,
                                               unsigned short* __restrict__ outp,
                                               int n, int bid, int tid) {
    constexpr int KS = K / 32;
    const int lane = tid & 63;
    const int wid = tid >> 6;
    const int m15 = lane & 15;
    const int q = lane >> 4;
    const int rA = bid * 64 + wid * 16 + m15;   // row this lane supplies to A

    bf16x8 a[KS];
    if constexpr (ABF16) {
        const unsigned short* A = (const unsigned short*)Asrc;
#pragma unroll
        for (int ks = 0; ks < KS; ++ks) {
            uint4 z = make_uint4(0u, 0u, 0u, 0u);
            if (rA < n) z = *(const uint4*)(A + (size_t)rA * K + ks * 32 + q * 8);
            a[ks] = __builtin_bit_cast(bf16x8, z);
        }
    } else {
        const float* A = (const float*)Asrc;
        float m = 1.0f;
        if constexpr (MSCALE) { if (rA < n) m = Mv[rA]; }
#pragma unroll
        for (int ks = 0; ks < KS; ++ks) {
            float4 lo = make_float4(0.f, 0.f, 0.f, 0.f);
            float4 hi = make_float4(0.f, 0.f, 0.f, 0.f);
            if (rA < n) {
                lo = *(const float4*)(A + (size_t)rA * K + ks * 32 + q * 8);
                hi = *(const float4*)(A + (size_t)rA * K + ks * 32 + q * 8 + 4);
            }
            union { bf16x8 v; unsigned short u[8]; } pk;
            pk.u[0] = f2bf(lo.x * m); pk.u[1] = f2bf(lo.y * m);
            pk.u[2] = f2bf(lo.z * m); pk.u[3] = f2bf(lo.w * m);
            pk.u[4] = f2bf(hi.x * m); pk.u[5] = f2bf(hi.y * m);
            pk.u[6] = f2bf(hi.z * m); pk.u[7] = f2bf(hi.w * m);
            a[ks] = pk.v;
        }
    }

#pragma unroll
    for (int nt = 0; nt < NTPAD / 16; ++nt) {
        f32x4 acc = {0.f, 0.f, 0.f, 0.f};
        const int bn = nt * 16 + m15;           // col this lane supplies to B
#pragma unroll
        for (int ks = 0; ks < KS; ++ks) {
            const uint4 z = *(const uint4*)(Wt + (size_t)bn * K + ks * 32 + q * 8);
            const bf16x8 b = __builtin_bit_cast(bf16x8, z);
            acc = __builtin_amdgcn_mfma_f32_16x16x32_bf16(a[ks], b, acc, 0, 0, 0);
        }
        const int gc = nt * 16 + m15;
#pragma unroll
        for (int rr = 0; rr < 4; ++rr) {
            const int gr = bid * 64 + wid * 16 + q * 4 + rr;
            bool ok = gr < n;
            if constexpr (NTPAD != COLS) ok = ok && (gc < COLS);
            if (ok) outp[(size_t)gr * COLS + gc] = f2bf(clampf(acc[rr]));
        }
    }
}

template <int K, int COLS, int NTPAD, bool ABF16, bool MSCALE>
__launch_bounds__(256)
__global__ void gemm_mfma(const void* __restrict__ A, const float* __restrict__ Mv,
                          const unsigned short* __restrict__ Wt,
                          unsigned short* __restrict__ out, int n) {
    gemm_mfma_body<K, COLS, NTPAD, ABF16, MSCALE>(A, Mv, Wt, out, n, blockIdx.x,
                                                  threadIdx.x);
}

// ---------------- fused LDS histogram (counting-sort rank) + gemm0 ----------------
// Blocks [0,NB): per-chunk LDS histogram over all bins (packed u16 pairs).
// Blocks [NB, NB+ceil(gemmBlocks/4)): gemm0, 4x 256-thread groups per block.

__launch_bounds__(1024)
__global__ void hist_gemm0(const int* __restrict__ row,
                           unsigned short* __restrict__ cntmat,
                           unsigned short* __restrict__ lrank, int E, int NB,
                           const float* __restrict__ x, const float* __restrict__ Mv,
                           const unsigned short* __restrict__ Wt0,
                           unsigned short* __restrict__ t_buf, int n) {
    __shared__ __align__(16) unsigned hcnt[NBINS / 2];   // 98KB: u16 bin pairs
    const int blk = blockIdx.x;
    const int t = threadIdx.x;
    if (blk < NB) {
        uint4* h4 = (uint4*)hcnt;
        const uint4 z4 = make_uint4(0u, 0u, 0u, 0u);
        for (int i = t; i < NBINS / 8; i += 1024) h4[i] = z4;
        __syncthreads();
        const int s = blk << HIST_EPB_LOG;
        const int e = min(E, s + HIST_EPB);
        for (int i = s + t; i < e; i += 1024) {
            const int r = row[i];               // r < n <= NBINS (host guarantees)
            const unsigned sh = (unsigned)(r & 1) << 4;
            const unsigned old = atomicAdd(&hcnt[r >> 1], 1u << sh);
            lrank[i] = (unsigned short)((old >> sh) & 0xffffu);
        }
        __syncthreads();
        uint4* dst = (uint4*)(cntmat + (size_t)blk * NBINS);
        for (int i = t; i < NBINS / 8; i += 1024) dst[i] = h4[i];
    } else {
        const int sub = t >> 8;                 // 4 gemm groups per block
        gemm_mfma_body<128, 128, 128, false, true>(x, Mv, Wt0, t_buf, n,
                                                   (blk - NB) * 4 + sub, t & 255);
    }
}

// ---------------- fused scan: rp + absolute chunk offsets, one kernel ----------------
// 196 resident blocks, 256 bins each. Publish/poll group totals via
// device-scope u64 atomics ({flag,total} packed) -> no cooperative launch,
// no dispatch-order assumption (grid <= capacity => all blocks resident =>
// spin terminates). cmabs[b][i] = rp_final[i] + sum_{b'<b} cm[b'][i].

__launch_bounds__(256)
__global__ void scan_one(const unsigned short* __restrict__ cm,
                         unsigned* __restrict__ cmabs, int* __restrict__ rp,
                         unsigned long long* __restrict__ gpub,
                         int n, int NB, int E) {
    __shared__ int sd[256];
    const int g = blockIdx.x;
    const int t = threadIdx.x;
    const int bin = g * 256 + t;

    // phase 1: this bin's total over all chunks (coalesced u16 loads)
    unsigned tot = 0;
    for (int b = 0; b < NB; ++b) tot += cm[(size_t)b * NBINS + bin];

    // block-inclusive scan over 256 bins
    sd[t] = (int)tot;
    __syncthreads();
    for (int off = 1; off < 256; off <<= 1) {
        int xv = (t >= off) ? sd[t - off] : 0;
        __syncthreads();
        sd[t] += xv;
        __syncthreads();
    }
    const int excl = sd[t] - (int)tot;
    const int gtot = sd[255];
    __syncthreads();                 // protect sd[255] before reuse

    // publish this group's total (flag in high word)
    if (t == 0)
        atomicExch(&gpub[g], (1ULL << 32) | (unsigned long long)(unsigned)gtot);

    // poll earlier groups' totals (each thread owns a subset)
    int my = 0;
    for (int p = t; p < g; p += 256) {
        unsigned long long v;
        do { v = atomicAdd(&gpub[p], 0ULL); } while ((v >> 32) == 0ULL);
        my += (int)(unsigned)v;
    }
    sd[t] = my;
    __syncthreads();
    for (int off = 128; off > 0; off >>= 1) {
        if (t < off) sd[t] += sd[t + off];
        __syncthreads();
    }
    const int base = sd[0];

    const int rpf = base + excl;     // rp_final[bin]
    if (bin < n) rp[bin] = rpf;
    if (g == SCAN_BLOCKS - 1 && t == 255) rp[n] = E;

    // phase 3: absolute per-chunk offsets (coalesced; cm is L2-warm)
    int run = rpf;
    for (int b = 0; b < NB; ++b) {
        cmabs[(size_t)b * NBINS + bin] = (unsigned)run;
        run += (int)cm[(size_t)b * NBINS + bin];
    }
}

// ---------------- scatter (atomic-free, ONE random gather per edge) ----------------
// cz[pos] = {col, vZ}; va[pos] = vA.

__global__ void scatter_kernel(const int* __restrict__ row, const int* __restrict__ col,
                               const float* __restrict__ vA, const float* __restrict__ vZ,
                               const unsigned* __restrict__ cmabs,
                               const unsigned short* __restrict__ lrank,
                               uint2* __restrict__ cz, float* __restrict__ va, int E) {
    int e = blockIdx.x * blockDim.x + threadIdx.x;
    if (e >= E) return;
    const int r = row[e];
    const int pos = (int)(cmabs[(size_t)(e >> HIST_EPB_LOG) * NBINS + r]
                          + (unsigned)lrank[e]);
    uint2 pk;
    pk.x = (unsigned)col[e];
    pk.y = __builtin_bit_cast(unsigned, vZ[e]);
    cz[pos] = pk;
    va[pos] = vA[e];
}

// ---------------- SpMM F=128: wave/row, 16-deep bursts; out = M⊙relu(...) bf16 ----------------

__launch_bounds__(256)
__global__ void spmm128_kernel(const uint2* __restrict__ cz,
                               const int* __restrict__ rp, const unsigned short* __restrict__ X,
                               const float* __restrict__ AM, const float* __restrict__ Mv,
                               const float* __restrict__ bias,
                               unsigned short* __restrict__ out, int n) {
    const int lane = threadIdx.x & 63;
    const int r = (int)((blockIdx.x * (unsigned)blockDim.x + threadIdx.x) >> 6);
    if (r >= n) return;
    const int s = __builtin_amdgcn_readfirstlane(rp[r]);
    const int e = __builtin_amdgcn_readfirstlane(rp[r + 1]);

    float acc0 = 0.0f, acc1 = 0.0f;
    for (int base = s; base < e; base += 64) {
        const int nn = min(64, e - base);
        int ci = 0; float vf = 0.0f;
        if (lane < nn) {
            const uint2 pk = cz[base + lane];
            ci = (int)pk.x;
            vf = __builtin_bit_cast(float, pk.y);
        }
        int j = 0;
        for (; j + 16 <= nn; j += 16) {         // avg deg = 16: one latency round
            unsigned u[16];
#pragma unroll
            for (int q = 0; q < 16; ++q) {
                const int cq = rl_i(ci, j + q);
                u[q] = *(const unsigned*)(X + (size_t)cq * 128 + lane * 2);
            }
#pragma unroll
            for (int q = 0; q < 16; ++q) {
                const float vq = rl_f(vf, j + q);
                acc0 += vq * bf_lo(u[q]);
                acc1 += vq * bf_hi(u[q]);
            }
        }
        for (; j + 8 <= nn; j += 8) {
            unsigned u[8];
#pragma unroll
            for (int q = 0; q < 8; ++q) {
                const int cq = rl_i(ci, j + q);
                u[q] = *(const unsigned*)(X + (size_t)cq * 128 + lane * 2);
            }
#pragma unroll
            for (int q = 0; q < 8; ++q) {
                const float vq = rl_f(vf, j + q);
                acc0 += vq * bf_lo(u[q]);
                acc1 += vq * bf_hi(u[q]);
            }
        }
        for (; j < nn; ++j) {
            const int cq = rl_i(ci, j);
            const float vq = rl_f(vf, j);
            const unsigned u = *(const unsigned*)(X + (size_t)cq * 128 + lane * 2);
            acc0 += vq * bf_lo(u);
            acc1 += vq * bf_hi(u);
        }
    }

    const float am = AM[r];
    const float mr = Mv[r];   // fold M (>=0): M⊙relu(y) = relu(M⊙y)
    const float o0 = fminf(fmaxf((acc0 * am + bias[2 * lane]) * mr, 0.0f), 1e30f);
    const float o1 = fminf(fmaxf((acc1 * am + bias[2 * lane + 1]) * mr, 0.0f), 1e30f);
    ((unsigned*)out)[(size_t)r * 64 + lane] = pack2bf(o0, o1);
}

// ---------------- SpMM F=64: 4 edges/wave (uint2/lane); out = relu(...) bf16 ----------------

__launch_bounds__(256)
__global__ void spmm64_kernel(const uint2* __restrict__ cz,
                              const int* __restrict__ rp, const unsigned short* __restrict__ X,
                              const float* __restrict__ AM, const float* __restrict__ bias,
                              unsigned short* __restrict__ out, int n) {
    const int lane = threadIdx.x & 63;
    const int g = lane >> 4;        // edge slot 0..3
    const int ls = lane & 15;       // feat quad: feats 4*ls..4*ls+3
    const int r = (int)((blockIdx.x * (unsigned)blockDim.x + threadIdx.x) >> 6);
    if (r >= n) return;
    const int s = __builtin_amdgcn_readfirstlane(rp[r]);
    const int e = __builtin_amdgcn_readfirstlane(rp[r + 1]);

    float a0 = 0.0f, a1 = 0.0f, a2 = 0.0f, a3 = 0.0f;
    for (int base = s; base < e; base += 64) {
        const int nn = min(64, e - base);
        int ci = 0; float vf = 0.0f;
        if (lane < nn) {
            const uint2 pk = cz[base + lane];
            ci = (int)pk.x;
            vf = __builtin_bit_cast(float, pk.y);
        }
        for (int j = 0; j < nn; j += 16) {
#pragma unroll
            for (int q = 0; q < 4; ++q) {
                const int jj = j + 4 * q + g;
                const bool ok = jj < nn;
                const int idx = jj & 63;
                const int c = __shfl(ci, idx);
                const float v = __shfl(vf, idx);
                if (ok) {
                    const uint2 u = *(const uint2*)(X + (size_t)c * 64 + ls * 4);
                    a0 += v * bf_lo(u.x);
                    a1 += v * bf_hi(u.x);
                    a2 += v * bf_lo(u.y);
                    a3 += v * bf_hi(u.y);
                }
            }
        }
    }
    a0 += __shfl_xor(a0, 16); a0 += __shfl_xor(a0, 32);
    a1 += __shfl_xor(a1, 16); a1 += __shfl_xor(a1, 32);
    a2 += __shfl_xor(a2, 16); a2 += __shfl_xor(a2, 32);
    a3 += __shfl_xor(a3, 16); a3 += __shfl_xor(a3, 32);

    if (lane < 16) {
        const float am = AM[r];
        const float o0 = fminf(fmaxf(a0 * am + bias[4 * ls + 0], 0.0f), 1e30f);
        const float o1 = fminf(fmaxf(a1 * am + bias[4 * ls + 1], 0.0f), 1e30f);
        const float o2 = fminf(fmaxf(a2 * am + bias[4 * ls + 2], 0.0f), 1e30f);
        const float o3 = fminf(fmaxf(a3 * am + bias[4 * ls + 3], 0.0f), 1e30f);
        uint2 w;
        w.x = pack2bf(o0, o1);
        w.y = pack2bf(o2, o3);
        *(uint2*)((unsigned*)out + (size_t)r * 32 + ls * 2) = w;
    }
}

// ---------------- SpMM F=40 + log_softmax: 3 edges/wave, 24 in flight ----------------

__launch_bounds__(256)
__global__ void spmm40_kernel(const uint2* __restrict__ cz,
                              const float* __restrict__ va,
                              const int* __restrict__ rp, const unsigned short* __restrict__ X,
                              const float* __restrict__ bias,
                              float* __restrict__ out, int n) {
    const int lane = threadIdx.x & 63;
    const int g = lane / 20;
    const int ls = lane - 20 * g;
    const bool active = g < 3;
    const int r = (int)((blockIdx.x * (unsigned)blockDim.x + threadIdx.x) >> 6);
    if (r >= n) return;
    const int s = __builtin_amdgcn_readfirstlane(rp[r]);
    const int e = __builtin_amdgcn_readfirstlane(rp[r + 1]);

    float acc0 = 0.0f, acc1 = 0.0f;
    for (int base = s; base < e; base += 64) {
        const int nn = min(64, e - base);
        int ci = 0; float vf = 0.0f;
        if (lane < nn) {
            ci = (int)cz[base + lane].x;
            vf = va[base + lane];        // adj (not adjZ) values
        }
        for (int j = 0; j < nn; j += 24) {
#pragma unroll
            for (int q = 0; q < 8; ++q) {
                const int jj = j + 3 * q + g;
                const bool ok = active && jj < nn;
                const int idx = jj & 63;
                const int c = __shfl(ci, idx);
                const float v = __shfl(vf, idx);
                if (ok) {
                    const unsigned u = *(const unsigned*)(X + (size_t)c * 40 + ls * 2);
                    acc0 += v * bf_lo(u);
                    acc1 += v * bf_hi(u);
                }
            }
        }
    }
    {
        const float a1 = __shfl(acc0, (lane + 20) & 63);
        const float a2 = __shfl(acc0, (lane + 40) & 63);
        const float b1 = __shfl(acc1, (lane + 20) & 63);
        const float b2 = __shfl(acc1, (lane + 40) & 63);
        acc0 += a1 + a2;
        acc1 += b1 + b2;
    }

    const bool own = lane < 20;
    const float vv0 = own ? fminf(fmaxf(acc0 + bias[2 * ls], -1e30f), 1e30f) : -INFINITY;
    const float vv1 = own ? fminf(fmaxf(acc1 + bias[2 * ls + 1], -1e30f), 1e30f) : -INFINITY;
    float mx = fmaxf(vv0, vv1);
#pragma unroll
    for (int off = 32; off > 0; off >>= 1) mx = fmaxf(mx, __shfl_xor(mx, off));
    float sum = own ? (expf(vv0 - mx) + expf(vv1 - mx)) : 0.0f;
#pragma unroll
    for (int off = 32; off > 0; off >>= 1) sum += __shfl_xor(sum, off);
    if (own) {
        const float lse = mx + logf(sum);
        *(float2*)(out + (size_t)r * 40 + ls * 2) = make_float2(vv0 - lse, vv1 - lse);
    }
}

// ---------------- launch ----------------

extern "C" void kernel_launch(void* const* d_in, const int* in_sizes, int n_in,
                              void* d_out, int out_size, void* d_ws, size_t ws_size,
                              hipStream_t stream) {
    const float* x    = (const float*)d_in[0];
    const float* M    = (const float*)d_in[1];
    const float* AM   = (const float*)d_in[2];
    const float* adjv = (const float*)d_in[3];
    const float* adjZ = (const float*)d_in[4];
    const float* W0   = (const float*)d_in[5];
    const float* b0   = (const float*)d_in[6];
    const float* W1   = (const float*)d_in[7];
    const float* b1   = (const float*)d_in[8];
    const float* W2   = (const float*)d_in[9];
    const float* b2   = (const float*)d_in[10];
    const int* row    = (const int*)d_in[11];
    const int* col    = (const int*)d_in[12];
    float* out = (float*)d_out;

    const int n = in_sizes[1];   // N  (must be <= NBINS = 50176)
    const int E = in_sizes[3];   // edges (<= NBMAX*32768 = 1M)

    // workspace layout (~61 MB):
    // t region (N*128 floats): t_buf bf16 (first half) + Wt arrays (tail)
    float* t_f   = (float*)d_ws;
    unsigned short* t_buf = (unsigned short*)t_f;           // N*128 bf16 gather target
    unsigned short* wt0 = t_buf + (size_t)n * 128;          // 128*128 (16B-aligned)
    unsigned short* wt1 = wt0 + 128 * 128;                  // 64*128
    unsigned short* wt2 = wt1 + 64 * 128;                   // 48*64
    float* h_f   = t_f + (size_t)n * 128;                   // N*128 floats reserved
    unsigned short* h_buf = (unsigned short*)h_f;           // bf16 h0 / h1
    // lrank + cntmat + cmabs alias the h region (dead before spmm128 writes h_buf)
    unsigned short* lrank  = (unsigned short*)h_f;          // E u16 local ranks
    unsigned short* cntmat = lrank + (size_t)E;             // [NBMAX][NBINS] u16
    unsigned* cmabs = (unsigned*)(cntmat + (size_t)NBMAX * NBINS);  // [NBMAX][NBINS] u32
    int* rp      = (int*)(h_f + (size_t)n * 128);           // N+1 (+1 align pad)
    unsigned long long* gpub = (unsigned long long*)(rp + n + 2);   // 256 u64 (8B-aligned)
    uint2* cz    = (uint2*)(gpub + 256);                    // E uint2 {col,vZ}
    float* va    = (float*)(cz + (size_t)E);                // E float (adj vals)

    const int NB = (E + HIST_EPB - 1) >> HIST_EPB_LOG;      // hist chunks (<=25)
    const int gemmBlocks = (n + 63) / 64;                   // 4-wave gemm groups
    const int gemmB4 = (gemmBlocks + 3) / 4;                // 1024-thr gemm blocks

    hipMemsetAsync(gpub, 0, 256 * sizeof(unsigned long long), stream);
    prep_wt<<<(128 * 128 + 64 * 128 + 48 * 64 + 255) / 256, 256, 0, stream>>>(
        W0, W1, W2, wt0, wt1, wt2);

    // fused LDS histogram (rank+count, no global atomics) + gemm0 MFMA
    hist_gemm0<<<NB + gemmB4, 1024, 0, stream>>>(row, cntmat, lrank, E, NB,
                                                 x, M, wt0, t_buf, n);

    // one-kernel scan: rp + absolute chunk offsets (publish/poll, resident grid)
    scan_one<<<SCAN_BLOCKS, 256, 0, stream>>>(cntmat, cmabs, rp, gpub, n, NB, E);

    scatter_kernel<<<(E + 255) / 256, 256, 0, stream>>>(row, col, adjv, adjZ,
                                                        cmabs, lrank, cz, va, E);

    const int spmmBlocks = (n + 3) / 4;   // 4 rows (waves) per block

    // layer 0 aggregate: h_buf = M⊙relu(AM⊙agg+b0) bf16 (overwrites lrank/cmabs alias)
    spmm128_kernel<<<spmmBlocks, 256, 0, stream>>>(cz, rp, t_buf, AM, M, b0, h_buf, n);
    // layer 1: t_buf = h_buf@W1 bf16 (M already folded)
    gemm_mfma<128, 64, 64, true, false><<<gemmBlocks, 256, 0, stream>>>(h_buf, nullptr, wt1,
                                                                        t_buf, n);
    spmm64_kernel<<<spmmBlocks, 256, 0, stream>>>(cz, rp, t_buf, AM, b1, h_buf, n);
    // layer 2: t_buf = h1@W2 bf16 (stride 40)
    gemm_mfma<64, 40, 48, true, false><<<gemmBlocks, 256, 0, stream>>>(h_buf, nullptr, wt2,
                                                                       t_buf, n);
    spmm40_kernel<<<spmmBlocks, 256, 0, stream>>>(cz, va, rp, t_buf, b2, out, n);
}